// Round 1
// baseline (288.417 us; speedup 1.0000x reference)
//
#include <hip/hip_runtime.h>
#include <hip/hip_bf16.h>

typedef __bf16 v8bf __attribute__((ext_vector_type(8)));
typedef float v4f __attribute__((ext_vector_type(4)));

#define GBL_AS(p) ((const __attribute__((address_space(1))) unsigned int*)(p))
#define LDS_AS(p) ((__attribute__((address_space(3))) unsigned int*)(p))

// ---------------- fp32 -> bf16 cast ----------------
__global__ void cast_f32_bf16(const float* __restrict__ src,
                              __hip_bfloat16* __restrict__ dst, int n) {
  int i = (blockIdx.x * 256 + threadIdx.x) * 4;
  if (i >= n) return;
  float4 f = *(const float4*)(src + i);
  union { __hip_bfloat16 h[4]; uint2 u; } pk;
  pk.h[0] = __float2bfloat16(f.x);
  pk.h[1] = __float2bfloat16(f.y);
  pk.h[2] = __float2bfloat16(f.z);
  pk.h[3] = __float2bfloat16(f.w);
  *(uint2*)(dst + i) = pk.u;
}

// ---------------- bf16 transpose (per-batch) ----------------
// src: [z][rows][cols] -> dst: [z][cols][rows]
__global__ void transpose_bf16(const __hip_bfloat16* __restrict__ src,
                               __hip_bfloat16* __restrict__ dst,
                               int rows, int cols) {
  __shared__ __hip_bfloat16 t[32][33];
  long boff = (long)blockIdx.z * rows * cols;
  src += boff; dst += boff;
  int c0 = blockIdx.x * 32, r0 = blockIdx.y * 32;
  int x = threadIdx.x;
#pragma unroll
  for (int i = 0; i < 4; ++i) {
    int y = threadIdx.y + i * 8;
    t[y][x] = src[(long)(r0 + y) * cols + (c0 + x)];
  }
  __syncthreads();
#pragma unroll
  for (int i = 0; i < 4; ++i) {
    int y = threadIdx.y + i * 8;
    dst[(long)(c0 + y) * rows + (r0 + x)] = t[x][y];
  }
}

// ---------------- NT GEMM: C[m,n] = scale * sum_k A[m,k]*B[n,k] ----------------
// 128x128 tile, BK=32, 256 threads (4 waves as 2x2 of 64x64), mfma 16x16x32 bf16.
// causal_mode: 0=none, 1=skip blocks fully above diagonal (scores),
//              2=limit K to mb+128 (PV with zero-padded weights).
// All of M,N multiples of 128; K and kend multiples of 32 (true for all uses).
template<bool OUT_BF16>
__global__ __launch_bounds__(256, 2)
void gemm_nt(const __hip_bfloat16* __restrict__ A, long sAb, int lda,
             const __hip_bfloat16* __restrict__ B, long sBb, int ldb,
             void* __restrict__ Cv, long sCb, int ldc,
             int K, float scale, int causal_mode) {
  const int tid = threadIdx.x;
  const int l = tid & 63, w = tid >> 6;
  const int nb = blockIdx.x * 128, mb = blockIdx.y * 128;
  if (causal_mode == 1 && nb > mb + 127) return;
  int kend = K;
  if (causal_mode == 2) kend = (K < mb + 128) ? K : (mb + 128);

  A += (long)blockIdx.z * sAb;
  B += (long)blockIdx.z * sBb;

  __shared__ alignas(16) __hip_bfloat16 As[128 * 32];
  __shared__ alignas(16) __hip_bfloat16 Bs[128 * 32];

  v4f acc[4][4] = {};
  const int wm = (w >> 1) * 64, wn = (w & 1) * 64;

  for (int k0 = 0; k0 < kend; k0 += 32) {
    // stage A and B tiles: 512 x 16B chunks each, 2 per thread per tile
#pragma unroll
    for (int t = 0; t < 2; ++t) {
      const int cbase = t * 256 + w * 64;        // wave-uniform chunk base
      const int c = cbase + l;
      const int row = c >> 2, col = (c & 3) << 3;
      __builtin_amdgcn_global_load_lds(
          GBL_AS(A + (long)(mb + row) * lda + (k0 + col)),
          LDS_AS(As + cbase * 8), 16, 0, 0);
      __builtin_amdgcn_global_load_lds(
          GBL_AS(B + (long)(nb + row) * ldb + (k0 + col)),
          LDS_AS(Bs + cbase * 8), 16, 0, 0);
    }
    __syncthreads();

    v8bf af[4], bfr[4];
#pragma unroll
    for (int i = 0; i < 4; ++i) {
      af[i]  = *(const v8bf*)(As + (wm + i * 16 + (l & 15)) * 32 + ((l >> 4) << 3));
      bfr[i] = *(const v8bf*)(Bs + (wn + i * 16 + (l & 15)) * 32 + ((l >> 4) << 3));
    }
#pragma unroll
    for (int i = 0; i < 4; ++i)
#pragma unroll
      for (int j = 0; j < 4; ++j)
        acc[i][j] = __builtin_amdgcn_mfma_f32_16x16x32_bf16(af[i], bfr[j], acc[i][j], 0, 0, 0);
    __syncthreads();
  }

  // epilogue: C/D layout col=lane&15, row=(lane>>4)*4+reg  [m89-verified]
  const int col0 = nb + wn + (l & 15);
  const int row0 = mb + wm + ((l >> 4) << 2);
  if constexpr (OUT_BF16) {
    __hip_bfloat16* C = (__hip_bfloat16*)Cv + (long)blockIdx.z * sCb;
#pragma unroll
    for (int i = 0; i < 4; ++i)
#pragma unroll
      for (int r = 0; r < 4; ++r) {
        long ro = (long)(row0 + i * 16 + r) * ldc;
#pragma unroll
        for (int j = 0; j < 4; ++j)
          C[ro + col0 + j * 16] = __float2bfloat16(acc[i][j][r] * scale);
      }
  } else {
    float* C = (float*)Cv + (long)blockIdx.z * sCb;
#pragma unroll
    for (int i = 0; i < 4; ++i)
#pragma unroll
      for (int r = 0; r < 4; ++r) {
        long ro = (long)(row0 + i * 16 + r) * ldc;
#pragma unroll
        for (int j = 0; j < 4; ++j)
          C[ro + col0 + j * 16] = acc[i][j][r] * scale;
      }
  }
}

// ---------------- causal row softmax, fp32 in -> bf16 out (in place) ----------------
// One block per row (grid = B*S). Row r: valid cols [0, q], q = r & (S-1).
// Writes 2048 bf16 weights into the first half of the row's fp32 storage.
__global__ __launch_bounds__(256)
void softmax_causal(float* __restrict__ scores) {
  const int row = blockIdx.x;
  const int q = row & 2047;
  float* s = scores + (long)row * 2048;
  __hip_bfloat16* wout = (__hip_bfloat16*)s;
  const int tid = threadIdx.x, l = tid & 63, w = tid >> 6;

  float v[8];
#pragma unroll
  for (int i = 0; i < 8; ++i) {
    int c = tid + i * 256;
    v[i] = (c <= q) ? s[c] : -__builtin_inff();
  }
  float m = v[0];
#pragma unroll
  for (int i = 1; i < 8; ++i) m = fmaxf(m, v[i]);
#pragma unroll
  for (int off = 32; off > 0; off >>= 1) m = fmaxf(m, __shfl_down(m, off));
  __shared__ float redm[4], reds[4];
  if (l == 0) redm[w] = m;
  __syncthreads();
  m = fmaxf(fmaxf(redm[0], redm[1]), fmaxf(redm[2], redm[3]));

  float e[8];
  float sum = 0.f;
#pragma unroll
  for (int i = 0; i < 8; ++i) { e[i] = expf(v[i] - m); sum += e[i]; }
#pragma unroll
  for (int off = 32; off > 0; off >>= 1) sum += __shfl_down(sum, off);
  if (l == 0) reds[w] = sum;
  __syncthreads();  // also guarantees all fp32 reads done before bf16 overwrite
  sum = reds[0] + reds[1] + reds[2] + reds[3];
  float inv = 1.0f / sum;
#pragma unroll
  for (int i = 0; i < 8; ++i) {
    int c = tid + i * 256;
    wout[c] = __float2bfloat16(e[i] * inv);
  }
}

// ---------------- launch ----------------
extern "C" void kernel_launch(void* const* d_in, const int* in_sizes, int n_in,
                              void* d_out, int out_size, void* d_ws, size_t ws_size,
                              hipStream_t stream) {
  const float* x  = (const float*)d_in[0];
  const float* Wq = (const float*)d_in[1];
  const float* Wk = (const float*)d_in[2];
  const float* Wv = (const float*)d_in[3];
  float* out = (float*)d_out;
  char* ws = (char*)d_ws;

  // ws layout (bytes):
  //   qkv bf16 [3][8192][1024]  @ 0         (48 MB)
  //   vT  bf16 [4][1024][2048]  @ 50331648  (16 MB)
  //   xb  bf16 [8192][1024]     @ 67108864  (16 MB, dead after proj)
  //   Wb  bf16 [3][1024][1024]  @ 83886080  ( 6 MB, dead after proj)
  //   scores fp32 [4][2048][2048] @ 67108864 (64 MB, overlaps dead xb/Wb)
  __hip_bfloat16* qkv = (__hip_bfloat16*)ws;
  __hip_bfloat16* vT  = (__hip_bfloat16*)(ws + 50331648);
  __hip_bfloat16* xb  = (__hip_bfloat16*)(ws + 67108864);
  __hip_bfloat16* Wb  = (__hip_bfloat16*)(ws + 83886080);
  float* scores       = (float*)(ws + 67108864);

  // casts
  cast_f32_bf16<<<8192, 256, 0, stream>>>(x, xb, 8388608);
  cast_f32_bf16<<<1024, 256, 0, stream>>>(Wq, Wb,            1048576);
  cast_f32_bf16<<<1024, 256, 0, stream>>>(Wk, Wb + 1048576,  1048576);
  cast_f32_bf16<<<1024, 256, 0, stream>>>(Wv, Wb + 2097152,  1048576);

  // qkv projections: batched over the 3 weights (A stride 0)
  gemm_nt<true><<<dim3(8, 64, 3), 256, 0, stream>>>(
      xb, 0L, 1024, Wb, 1048576L, 1024, qkv, 8388608L, 1024,
      1024, 1.0f, 0);

  // v -> vT (per batch)
  transpose_bf16<<<dim3(32, 64, 4), dim3(32, 8), 0, stream>>>(
      qkv + 16777216, vT, 2048, 1024);

  // scores = (q @ k^T) / 32, fp32, skip fully-masked blocks
  gemm_nt<false><<<dim3(16, 16, 4), 256, 0, stream>>>(
      qkv, 2097152L, 1024, qkv + 8388608, 2097152L, 1024,
      scores, 4194304L, 2048, 1024, 0.03125f, 1);

  // softmax rows -> bf16 weights in place
  softmax_causal<<<8192, 256, 0, stream>>>(scores);

  // out = weights @ v  (= weights @ vT^T), causal K-limit
  gemm_nt<false><<<dim3(8, 16, 4), 256, 0, stream>>>(
      (__hip_bfloat16*)scores, 8388608L, 4096, vT, 2097152L, 2048,
      out, 2097152L, 1024, 2048, 1.0f, 2);
}

// Round 2
// 263.626 us; speedup vs baseline: 1.0940x; 1.0940x over previous
//
#include <hip/hip_runtime.h>
#include <hip/hip_bf16.h>

typedef __bf16 v8bf __attribute__((ext_vector_type(8)));
typedef float v4f __attribute__((ext_vector_type(4)));

#define GBL_AS(p) ((const __attribute__((address_space(1))) unsigned int*)(p))
#define LDS_AS(p) ((__attribute__((address_space(3))) unsigned int*)(p))

// ---------------- fp32 -> bf16 cast (x) ----------------
__global__ void cast_f32_bf16(const float* __restrict__ src,
                              __hip_bfloat16* __restrict__ dst, int n) {
  int i = (blockIdx.x * 256 + threadIdx.x) * 4;
  if (i >= n) return;
  float4 f = *(const float4*)(src + i);
  union { __hip_bfloat16 h[4]; uint2 u; } pk;
  pk.h[0] = __float2bfloat16(f.x);
  pk.h[1] = __float2bfloat16(f.y);
  pk.h[2] = __float2bfloat16(f.z);
  pk.h[3] = __float2bfloat16(f.w);
  *(uint2*)(dst + i) = pk.u;
}

// ---------------- fp32 -> bf16 cast, 3 weight tensors in one dispatch ----------------
__global__ void cast_w3(const float* __restrict__ a, const float* __restrict__ b,
                        const float* __restrict__ c, __hip_bfloat16* __restrict__ dst) {
  int seg = blockIdx.x >> 10;                      // 1024 blocks per 1M-element weight
  const float* src = seg == 0 ? a : (seg == 1 ? b : c);
  int i = ((blockIdx.x & 1023) * 256 + threadIdx.x) * 4;
  float4 f = *(const float4*)(src + i);
  union { __hip_bfloat16 h[4]; uint2 u; } pk;
  pk.h[0] = __float2bfloat16(f.x);
  pk.h[1] = __float2bfloat16(f.y);
  pk.h[2] = __float2bfloat16(f.z);
  pk.h[3] = __float2bfloat16(f.w);
  *(uint2*)(dst + seg * 1048576 + i) = pk.u;
}

// ---------------- bf16 transpose (per-batch): [z][rows][cols] -> [z][cols][rows] ----------------
__global__ void transpose_bf16(const __hip_bfloat16* __restrict__ src,
                               __hip_bfloat16* __restrict__ dst,
                               int rows, int cols) {
  __shared__ __hip_bfloat16 t[32][33];
  long boff = (long)blockIdx.z * rows * cols;
  src += boff; dst += boff;
  int c0 = blockIdx.x * 32, r0 = blockIdx.y * 32;
  int x = threadIdx.x;
#pragma unroll
  for (int i = 0; i < 4; ++i) {
    int y = threadIdx.y + i * 8;
    t[y][x] = src[(long)(r0 + y) * cols + (c0 + x)];
  }
  __syncthreads();
#pragma unroll
  for (int i = 0; i < 4; ++i) {
    int y = threadIdx.y + i * 8;
    dst[(long)(c0 + y) * rows + (r0 + x)] = t[x][y];
  }
}

// ---------------- NT GEMM: C[m,n] = f( scale * sum_k A[m,k]*B[n,k] ) ----------------
// 128x128 tile, BK=32, 256 threads (4 waves as 2x2 of 64x64), mfma 16x16x32 bf16.
// MODE 0: bf16 out, z folded into blockIdx.x (x = z*8 + nb8)        [proj]
// MODE 1: skip blocks above diagonal; epilogue p = (n<=m)?exp(s*scale):0, bf16 out  [scores->P]
// MODE 2: K limited to mb+128; fp32 out scaled by inv_sums[z*2048+m]  [PV]
template<int MODE>
__global__ __launch_bounds__(256, 2)
void gemm_nt(const __hip_bfloat16* __restrict__ A, long sAb, int lda,
             const __hip_bfloat16* __restrict__ B, long sBb, int ldb,
             void* __restrict__ Cv, long sCb, int ldc,
             int K, float scale, const float* __restrict__ inv_sums) {
  const int tid = threadIdx.x;
  const int l = tid & 63, w = tid >> 6;
  int z, nb;
  if (MODE == 0) { z = blockIdx.x >> 3; nb = (blockIdx.x & 7) << 7; }
  else           { z = blockIdx.z;      nb = blockIdx.x << 7; }
  const int mb = blockIdx.y * 128;
  if (MODE == 1 && nb > mb + 127) return;
  int kend = K;
  if (MODE == 2) kend = (K < mb + 128) ? K : (mb + 128);

  A += (long)z * sAb;
  B += (long)z * sBb;

  __shared__ alignas(16) __hip_bfloat16 As[128 * 32];
  __shared__ alignas(16) __hip_bfloat16 Bs[128 * 32];

  v4f acc[4][4] = {};
  const int wm = (w >> 1) * 64, wn = (w & 1) * 64;

  for (int k0 = 0; k0 < kend; k0 += 32) {
#pragma unroll
    for (int t = 0; t < 2; ++t) {
      const int cbase = t * 256 + w * 64;        // wave-uniform chunk base
      const int c = cbase + l;
      const int row = c >> 2, col = (c & 3) << 3;
      __builtin_amdgcn_global_load_lds(
          GBL_AS(A + (long)(mb + row) * lda + (k0 + col)),
          LDS_AS(As + cbase * 8), 16, 0, 0);
      __builtin_amdgcn_global_load_lds(
          GBL_AS(B + (long)(nb + row) * ldb + (k0 + col)),
          LDS_AS(Bs + cbase * 8), 16, 0, 0);
    }
    __syncthreads();

    v8bf af[4], bfr[4];
#pragma unroll
    for (int i = 0; i < 4; ++i) {
      af[i]  = *(const v8bf*)(As + (wm + i * 16 + (l & 15)) * 32 + ((l >> 4) << 3));
      bfr[i] = *(const v8bf*)(Bs + (wn + i * 16 + (l & 15)) * 32 + ((l >> 4) << 3));
    }
#pragma unroll
    for (int i = 0; i < 4; ++i)
#pragma unroll
      for (int j = 0; j < 4; ++j)
        acc[i][j] = __builtin_amdgcn_mfma_f32_16x16x32_bf16(af[i], bfr[j], acc[i][j], 0, 0, 0);
    __syncthreads();
  }

  // epilogue: C/D layout col=lane&15, row=(lane>>4)*4+reg  [m89-verified]
  const int col0 = nb + wn + (l & 15);
  const int row0 = mb + wm + ((l >> 4) << 2);
  if constexpr (MODE == 0) {
    __hip_bfloat16* C = (__hip_bfloat16*)Cv + (long)z * sCb;
#pragma unroll
    for (int i = 0; i < 4; ++i)
#pragma unroll
      for (int r = 0; r < 4; ++r) {
        long ro = (long)(row0 + i * 16 + r) * ldc;
#pragma unroll
        for (int j = 0; j < 4; ++j)
          C[ro + col0 + j * 16] = __float2bfloat16(acc[i][j][r] * scale);
      }
  } else if constexpr (MODE == 1) {
    __hip_bfloat16* C = (__hip_bfloat16*)Cv + (long)z * sCb;
#pragma unroll
    for (int i = 0; i < 4; ++i)
#pragma unroll
      for (int r = 0; r < 4; ++r) {
        const int m = row0 + i * 16 + r;
        long ro = (long)m * ldc;
#pragma unroll
        for (int j = 0; j < 4; ++j) {
          const int n = col0 + j * 16;
          float p = (n <= m) ? __expf(acc[i][j][r] * scale) : 0.0f;
          C[ro + n] = __float2bfloat16(p);
        }
      }
  } else {
    float* C = (float*)Cv + (long)z * sCb;
    const float* inv = inv_sums + z * 2048;
#pragma unroll
    for (int i = 0; i < 4; ++i)
#pragma unroll
      for (int r = 0; r < 4; ++r) {
        const int m = row0 + i * 16 + r;
        const float s = inv[m];
        long ro = (long)m * ldc;
#pragma unroll
        for (int j = 0; j < 4; ++j)
          C[ro + col0 + j * 16] = acc[i][j][r] * s;
      }
  }
}

// ---------------- row sums of P -> 1/sum ----------------
// One wave per row (4 rows/block, grid 2048). Row r valid cols [0, rend),
// rend = ((q>>7)+1)*128 (cols beyond are unwritten poison; cols (q, rend) are 0).
__global__ __launch_bounds__(256)
void rowsum_inv(const __hip_bfloat16* __restrict__ P, float* __restrict__ inv) {
  const int w = threadIdx.x >> 6, l = threadIdx.x & 63;
  const int row = blockIdx.x * 4 + w;            // 0..8191
  const int q = row & 2047;
  const int rend = ((q >> 7) + 1) << 7;
  const __hip_bfloat16* p = P + (long)row * 2048;
  float sum = 0.f;
  for (int c0 = l * 8; c0 < rend; c0 += 512) {
    union { v8bf v; unsigned short us[8]; } u;
    u.v = *(const v8bf*)(p + c0);
#pragma unroll
    for (int j = 0; j < 8; ++j)
      sum += __uint_as_float((unsigned)u.us[j] << 16);
  }
#pragma unroll
  for (int off = 32; off > 0; off >>= 1) sum += __shfl_down(sum, off);
  if (l == 0) inv[row] = 1.0f / sum;
}

// ---------------- launch ----------------
extern "C" void kernel_launch(void* const* d_in, const int* in_sizes, int n_in,
                              void* d_out, int out_size, void* d_ws, size_t ws_size,
                              hipStream_t stream) {
  const float* x  = (const float*)d_in[0];
  const float* Wq = (const float*)d_in[1];
  const float* Wk = (const float*)d_in[2];
  const float* Wv = (const float*)d_in[3];
  float* out = (float*)d_out;
  char* ws = (char*)d_ws;

  // ws layout (bytes):
  //   qkv bf16 [3][8192][1024]   @ 0          (48 MB)
  //   vT  bf16 [4][1024][2048]   @ 50331648   (16 MB)
  //   xb  bf16 [8192][1024]      @ 67108864   (16 MB, dead after proj)
  //   Wb  bf16 [3][1024][1024]   @ 83886080   ( 6 MB, dead after proj)
  //   P   bf16 [4][2048][2048]   @ 67108864   (32 MB, overlaps dead xb/Wb)
  //   inv fp32 [8192]            @ 100663296  (32 KB)
  __hip_bfloat16* qkv = (__hip_bfloat16*)ws;
  __hip_bfloat16* vT  = (__hip_bfloat16*)(ws + 50331648);
  __hip_bfloat16* xb  = (__hip_bfloat16*)(ws + 67108864);
  __hip_bfloat16* Wb  = (__hip_bfloat16*)(ws + 83886080);
  __hip_bfloat16* P   = (__hip_bfloat16*)(ws + 67108864);
  float* inv          = (float*)(ws + 100663296);

  // casts
  cast_f32_bf16<<<8192, 256, 0, stream>>>(x, xb, 8388608);
  cast_w3<<<3072, 256, 0, stream>>>(Wq, Wk, Wv, Wb);

  // qkv projections, z folded into x for A-tile/L2 locality
  gemm_nt<0><<<dim3(24, 64, 1), 256, 0, stream>>>(
      xb, 0L, 1024, Wb, 1048576L, 1024, qkv, 8388608L, 1024,
      1024, 1.0f, nullptr);

  // v -> vT (per batch)
  transpose_bf16<<<dim3(32, 64, 4), dim3(32, 8), 0, stream>>>(
      qkv + 16777216, vT, 2048, 1024);

  // P = exp((q@k^T)/32) with causal mask, bf16 (max-free softmax: |s/32| <~ 3)
  gemm_nt<1><<<dim3(16, 16, 4), 256, 0, stream>>>(
      qkv, 2097152L, 1024, qkv + 8388608, 2097152L, 1024,
      P, 4194304L, 2048, 1024, 0.03125f, nullptr);

  // row sums -> 1/sum
  rowsum_inv<<<2048, 256, 0, stream>>>(P, inv);

  // out = (P @ vT^T) * inv_rowsum, causal K-limit
  gemm_nt<2><<<dim3(8, 16, 4), 256, 0, stream>>>(
      P, 4194304L, 2048, vT, 2097152L, 2048,
      out, 2097152L, 1024, 2048, 1.0f, inv);
}

// Round 3
// 245.169 us; speedup vs baseline: 1.1764x; 1.0753x over previous
//
#include <hip/hip_runtime.h>
#include <hip/hip_bf16.h>

typedef __bf16 v8bf __attribute__((ext_vector_type(8)));
typedef float v4f __attribute__((ext_vector_type(4)));

#define GBL_AS(p) ((const __attribute__((address_space(1))) unsigned int*)(p))
#define LDS_AS(p) ((__attribute__((address_space(3))) unsigned int*)(p))

// ---------------- fp32 -> bf16 cast (x) ----------------
__global__ void cast_f32_bf16(const float* __restrict__ src,
                              __hip_bfloat16* __restrict__ dst, int n) {
  int i = (blockIdx.x * 256 + threadIdx.x) * 4;
  if (i >= n) return;
  float4 f = *(const float4*)(src + i);
  union { __hip_bfloat16 h[4]; uint2 u; } pk;
  pk.h[0] = __float2bfloat16(f.x);
  pk.h[1] = __float2bfloat16(f.y);
  pk.h[2] = __float2bfloat16(f.z);
  pk.h[3] = __float2bfloat16(f.w);
  *(uint2*)(dst + i) = pk.u;
}

// ---------------- fp32 -> bf16 cast, 3 weight tensors in one dispatch ----------------
__global__ void cast_w3(const float* __restrict__ a, const float* __restrict__ b,
                        const float* __restrict__ c, __hip_bfloat16* __restrict__ dst) {
  int seg = blockIdx.x >> 10;
  const float* src = seg == 0 ? a : (seg == 1 ? b : c);
  int i = ((blockIdx.x & 1023) * 256 + threadIdx.x) * 4;
  float4 f = *(const float4*)(src + i);
  union { __hip_bfloat16 h[4]; uint2 u; } pk;
  pk.h[0] = __float2bfloat16(f.x);
  pk.h[1] = __float2bfloat16(f.y);
  pk.h[2] = __float2bfloat16(f.z);
  pk.h[3] = __float2bfloat16(f.w);
  *(uint2*)(dst + seg * 1048576 + i) = pk.u;
}

// ---------------- bf16 transpose (per-batch): [z][rows][cols] -> [z][cols][rows] ----------------
__global__ void transpose_bf16(const __hip_bfloat16* __restrict__ src,
                               __hip_bfloat16* __restrict__ dst,
                               int rows, int cols) {
  __shared__ __hip_bfloat16 t[32][33];
  long boff = (long)blockIdx.z * rows * cols;
  src += boff; dst += boff;
  int c0 = blockIdx.x * 32, r0 = blockIdx.y * 32;
  int x = threadIdx.x;
#pragma unroll
  for (int i = 0; i < 4; ++i) {
    int y = threadIdx.y + i * 8;
    t[y][x] = src[(long)(r0 + y) * cols + (c0 + x)];
  }
  __syncthreads();
#pragma unroll
  for (int i = 0; i < 4; ++i) {
    int y = threadIdx.y + i * 8;
    dst[(long)(c0 + y) * rows + (r0 + x)] = t[x][y];
  }
}

// ---------------- NT GEMM: C[m,n] = f( scale * sum_k A[m,k]*B[n,k] ) ----------------
// 128x128 tile, BK=32, 256 threads (4 waves as 2x2 of 64x64), mfma 16x16x32 bf16.
// 4 blocks/CU (launch_bounds 256,4; ~120 unified VGPR, 16KB LDS).
// MODE 0: proj. grid (24,64): x = z*8 + nb8, y = mb. bf16 out.
// MODE 1: scores->P. flat triangular grid (544): id -> (z, mb>=nb). epilogue
//         p = (n<=m)?exp(s*scale):0, bf16 out, fused row-sum atomicAdd into sums.
// MODE 2: PV. flat paired grid (512): blocks id and id+256 get mirrored mb so
//         co-resident pairs have constant total K-work. fp32 out * 1/sums[m].
template<int MODE>
__global__ __launch_bounds__(256, 4)
void gemm_nt(const __hip_bfloat16* __restrict__ A, long sAb, int lda,
             const __hip_bfloat16* __restrict__ B, long sBb, int ldb,
             void* __restrict__ Cv, long sCb, int ldc,
             int K, float scale, float* __restrict__ sums) {
  const int tid = threadIdx.x;
  const int l = tid & 63, w = tid >> 6;
  int z, nb, mb, kend = K;
  if (MODE == 0) {
    z = blockIdx.x >> 3; nb = (blockIdx.x & 7) << 7; mb = blockIdx.y << 7;
  } else if (MODE == 1) {
    const int id = blockIdx.x;
    z = id & 3;
    const int t = id >> 2;                         // 0..135 triangular index
    int m = (int)((__builtin_sqrtf(8.0f * t + 1.0f) - 1.0f) * 0.5f);
    while ((m + 1) * (m + 2) / 2 <= t) ++m;
    while (m * (m + 1) / 2 > t) --m;
    mb = m << 7;
    nb = (t - m * (m + 1) / 2) << 7;
  } else {
    const int id = blockIdx.x;
    const int half = id >> 8, r8 = id & 255;
    const int m = r8 >> 4, low = r8 & 15;
    nb = (low >> 1) << 7;
    z = (half << 1) | (low & 1);
    const int mi = half ? (15 - m) : m;            // mirrored: pair work constant
    mb = mi << 7;
    kend = (mi + 1) << 7;                          // causal K-limit
  }

  A += (long)z * sAb;
  B += (long)z * sBb;

  __shared__ alignas(16) __hip_bfloat16 As[128 * 32];
  __shared__ alignas(16) __hip_bfloat16 Bs[128 * 32];

  v4f acc[4][4] = {};
  const int wm = (w >> 1) * 64, wn = (w & 1) * 64;

  for (int k0 = 0; k0 < kend; k0 += 32) {
#pragma unroll
    for (int t = 0; t < 2; ++t) {
      const int cbase = t * 256 + w * 64;          // wave-uniform chunk base
      const int c = cbase + l;
      const int row = c >> 2, col = (c & 3) << 3;
      __builtin_amdgcn_global_load_lds(
          GBL_AS(A + (long)(mb + row) * lda + (k0 + col)),
          LDS_AS(As + cbase * 8), 16, 0, 0);
      __builtin_amdgcn_global_load_lds(
          GBL_AS(B + (long)(nb + row) * ldb + (k0 + col)),
          LDS_AS(Bs + cbase * 8), 16, 0, 0);
    }
    __syncthreads();

    v8bf af[4], bfr[4];
#pragma unroll
    for (int i = 0; i < 4; ++i) {
      af[i]  = *(const v8bf*)(As + (wm + i * 16 + (l & 15)) * 32 + ((l >> 4) << 3));
      bfr[i] = *(const v8bf*)(Bs + (wn + i * 16 + (l & 15)) * 32 + ((l >> 4) << 3));
    }
#pragma unroll
    for (int i = 0; i < 4; ++i)
#pragma unroll
      for (int j = 0; j < 4; ++j)
        acc[i][j] = __builtin_amdgcn_mfma_f32_16x16x32_bf16(af[i], bfr[j], acc[i][j], 0, 0, 0);
    __syncthreads();
  }

  // epilogue: C/D layout col=lane&15, row=(lane>>4)*4+reg  [m89-verified]
  const int col0 = nb + wn + (l & 15);
  const int row0 = mb + wm + ((l >> 4) << 2);
  if constexpr (MODE == 0) {
    __hip_bfloat16* C = (__hip_bfloat16*)Cv + (long)z * sCb;
#pragma unroll
    for (int i = 0; i < 4; ++i)
#pragma unroll
      for (int r = 0; r < 4; ++r) {
        long ro = (long)(row0 + i * 16 + r) * ldc;
#pragma unroll
        for (int j = 0; j < 4; ++j)
          C[ro + col0 + j * 16] = __float2bfloat16(acc[i][j][r] * scale);
      }
  } else if constexpr (MODE == 1) {
    __hip_bfloat16* C = (__hip_bfloat16*)Cv + (long)z * sCb;
    float* srow = sums + z * 2048;
#pragma unroll
    for (int i = 0; i < 4; ++i)
#pragma unroll
      for (int r = 0; r < 4; ++r) {
        const int m = row0 + i * 16 + r;
        long ro = (long)m * ldc;
        float sp = 0.f;
#pragma unroll
        for (int j = 0; j < 4; ++j) {
          const int n = col0 + j * 16;
          float p = (n <= m) ? __expf(acc[i][j][r] * scale) : 0.0f;
          sp += p;
          C[ro + n] = __float2bfloat16(p);
        }
        // reduce this row's 64-col slice across the 16-lane group
        sp += __shfl_xor(sp, 1);
        sp += __shfl_xor(sp, 2);
        sp += __shfl_xor(sp, 4);
        sp += __shfl_xor(sp, 8);
        if ((l & 15) == 0) atomicAdd(&srow[m], sp);
      }
  } else {
    float* C = (float*)Cv + (long)z * sCb;
    const float* srow = sums + z * 2048;
#pragma unroll
    for (int i = 0; i < 4; ++i)
#pragma unroll
      for (int r = 0; r < 4; ++r) {
        const int m = row0 + i * 16 + r;
        const float s = 1.0f / srow[m];
        long ro = (long)m * ldc;
#pragma unroll
        for (int j = 0; j < 4; ++j)
          C[ro + col0 + j * 16] = acc[i][j][r] * s;
      }
  }
}

// ---------------- launch ----------------
extern "C" void kernel_launch(void* const* d_in, const int* in_sizes, int n_in,
                              void* d_out, int out_size, void* d_ws, size_t ws_size,
                              hipStream_t stream) {
  const float* x  = (const float*)d_in[0];
  const float* Wq = (const float*)d_in[1];
  const float* Wk = (const float*)d_in[2];
  const float* Wv = (const float*)d_in[3];
  float* out = (float*)d_out;
  char* ws = (char*)d_ws;

  // ws layout (bytes):
  //   qkv bf16 [3][8192][1024]   @ 0          (48 MB)
  //   vT  bf16 [4][1024][2048]   @ 50331648   (16 MB)
  //   xb  bf16 [8192][1024]      @ 67108864   (16 MB, dead after proj)
  //   Wb  bf16 [3][1024][1024]   @ 83886080   ( 6 MB, dead after proj)
  //   P   bf16 [4][2048][2048]   @ 67108864   (32 MB, overlaps dead xb/Wb)
  //   sums fp32 [8192]           @ 100663296  (32 KB)
  __hip_bfloat16* qkv = (__hip_bfloat16*)ws;
  __hip_bfloat16* vT  = (__hip_bfloat16*)(ws + 50331648);
  __hip_bfloat16* xb  = (__hip_bfloat16*)(ws + 67108864);
  __hip_bfloat16* Wb  = (__hip_bfloat16*)(ws + 83886080);
  __hip_bfloat16* P   = (__hip_bfloat16*)(ws + 67108864);
  float* sums         = (float*)(ws + 100663296);

  // zero the fused-rowsum accumulators (harness poisons ws with 0xAA)
  hipMemsetAsync(sums, 0, 8192 * sizeof(float), stream);

  // casts
  cast_f32_bf16<<<8192, 256, 0, stream>>>(x, xb, 8388608);
  cast_w3<<<3072, 256, 0, stream>>>(Wq, Wk, Wv, Wb);

  // qkv projections, z folded into x for A-tile/L2 locality
  gemm_nt<0><<<dim3(24, 64, 1), 256, 0, stream>>>(
      xb, 0L, 1024, Wb, 1048576L, 1024, qkv, 8388608L, 1024,
      1024, 1.0f, nullptr);

  // v -> vT (per batch)
  transpose_bf16<<<dim3(32, 64, 4), dim3(32, 8), 0, stream>>>(
      qkv + 16777216, vT, 2048, 1024);

  // P = exp((q@k^T)/32) causal, bf16, fused row-sums (triangular grid: 136*4)
  gemm_nt<1><<<dim3(544, 1, 1), 256, 0, stream>>>(
      qkv, 2097152L, 1024, qkv + 8388608, 2097152L, 1024,
      P, 4194304L, 2048, 1024, 0.03125f, sums);

  // out = (P @ vT^T) / rowsum, causal K-limit, pair-balanced flat grid
  gemm_nt<2><<<dim3(512, 1, 1), 256, 0, stream>>>(
      P, 4194304L, 2048, vT, 2097152L, 2048,
      out, 2097152L, 1024, 2048, 1.0f, sums);
}